// Round 14
// baseline (184.341 us; speedup 1.0000x reference)
//
#include <hip/hip_runtime.h>

typedef unsigned short u16;
typedef unsigned int u32;
typedef short bf16x8 __attribute__((ext_vector_type(8)));  // 8 bf16 (4 VGPRs)
typedef float f32x4 __attribute__((ext_vector_type(4)));
typedef float f32x2 __attribute__((ext_vector_type(2)));
typedef u32 u32x2 __attribute__((ext_vector_type(2)));

#define PP 4096
#define KPT 9

__device__ __forceinline__ u16 f2b(float f) {
    union { float f; unsigned int u; } v; v.f = f;
    unsigned int u = v.u;
    unsigned int r = u + 0x7FFFu + ((u >> 16) & 1u);   // RNE
    return (u16)(r >> 16);
}
__device__ __forceinline__ float b2f(u16 b) {
    union { unsigned int u; float f; } v; v.u = ((unsigned int)b) << 16;
    return v.f;
}
__device__ __forceinline__ f32x2 unpk2(u32 u) {
    f32x2 r;
    r.x = __uint_as_float(u << 16);
    r.y = __uint_as_float(u & 0xFFFF0000u);
    return r;
}

// ---- fused: weight transpose/convert (blocks 0..1023) + composite offset/mask
//      weight fold (blocks 1024..1791) ----
__global__ __launch_bounds__(256) void prep_weights(
        const float* __restrict__ qkv_w, const float* __restrict__ proj_w,
        const float* __restrict__ off_pconv_w, const float* __restrict__ off_w,
        const float* __restrict__ off_b, const float* __restrict__ mask_pconv_w,
        const float* __restrict__ mask_w, const float* __restrict__ mask_b,
        u16* __restrict__ qkv_wT_b, u16* __restrict__ proj_wT_b,
        u16* __restrict__ cwT_b, float* __restrict__ cb) {
    int blk = blockIdx.x;
    if (blk < 1024) {
        int idx = blk * 256 + threadIdx.x;     // 262144 total
        if (idx < 196608) {                    // qkv_w [256][768] -> T [768][256]
            int r = idx / 768, c = idx % 768;
            qkv_wT_b[c * 256 + r] = f2b(qkv_w[idx]);
        } else {
            int i3 = idx - 196608;             // proj_w [256][256] -> T
            int r = i3 >> 8, c = i3 & 255;
            proj_wT_b[c * 256 + r] = f2b(proj_w[i3]);
        }
        return;
    }
    int k = blk - 1024;      // 0..767
    int o = threadIdx.x;     // active 0..159
    if (o >= 160) return;
    float val = 0.f;
    if (o < 153) {
        if (k < 576) {
            int patch = k >> 6, i = k & 63;
            if (o < 144) {
                int g = o / 18, oo = o % 18;
                for (int c = 0; c < 64; c++)
                    val += off_w[(g * 18 + oo) * 256 + c] *
                           off_pconv_w[((g * 64 + c) * 64 + i) * 9 + patch];
            } else {
                int oo = o - 144;
                for (int c = 0; c < 64; c++)
                    val += mask_w[oo * 256 + c] * mask_pconv_w[(c * 64 + i) * 9 + patch];
            }
        } else {
            int j = k - 576;
            if (o < 144) {
                int g = o / 18, oo = o % 18;
                val = off_w[(g * 18 + oo) * 256 + 64 + j];
            } else {
                val = mask_w[(o - 144) * 256 + 64 + j];
            }
        }
    }
    cwT_b[o * 768 + k] = f2b(val);
    if (k == 0) {
        float bv = 0.f;
        if (o < 144) {
            int g = o / 18, oo = o % 18;
            const float PTSf[18] = {-1,-1,-1,0,-1,1,0,-1,0,0,0,1,1,-1,1,0,1,1};
            bv = off_b[g * 18 + oo] + PTSf[oo] * (float)(2 * g + 1);
        } else if (o < 153) {
            bv = mask_b[o - 144];
        }
        cb[o] = bv;
    }
}

// ---- MFMA GEMM (qkv): out = A[M][K] * BT[N][K]^T + bias, K compile-time ----
// BM=64, BN=64, BK=32, 256 threads (4 waves, 2x2), wave tile 32x32
template<bool OUT_BF16, bool A_F32, int KD>
__global__ __launch_bounds__(256) void mfma_gemm(
        const void* __restrict__ Av, const u16* __restrict__ BT,
        const float* __restrict__ bias, void* __restrict__ out, int N) {
    __shared__ u16 As[64][40];
    __shared__ u16 Bs[64][40];
    int tid = threadIdx.x;
    int row0 = blockIdx.x * 64, col0 = blockIdx.y * 64;
    int wid = tid >> 6, lane = tid & 63;
    int wr = wid >> 1, wc = wid & 1;
    int l15 = lane & 15, lhi = lane >> 4;
    f32x4 acc[2][2] = {};
    #pragma unroll
    for (int k0 = 0; k0 < KD; k0 += 32) {
        {
            int r = tid >> 2, kc = (tid & 3) * 8;
            if (A_F32) {
                const float* Af = (const float*)Av;
                f32x4 a0 = *(const f32x4*)&Af[(size_t)(row0 + r) * KD + k0 + kc];
                f32x4 a1 = *(const f32x4*)&Af[(size_t)(row0 + r) * KD + k0 + kc + 4];
                bf16x8 v;
                #pragma unroll
                for (int j = 0; j < 4; j++) { v[j] = (short)f2b(a0[j]); v[4+j] = (short)f2b(a1[j]); }
                *(bf16x8*)&As[r][kc] = v;
            } else {
                const u16* Ab = (const u16*)Av;
                *(bf16x8*)&As[r][kc] = *(const bf16x8*)&Ab[(size_t)(row0 + r) * KD + k0 + kc];
            }
            *(bf16x8*)&Bs[r][kc] = *(const bf16x8*)&BT[(size_t)(col0 + r) * KD + k0 + kc];
        }
        __syncthreads();
        bf16x8 bfr[2], afr[2];
        #pragma unroll
        for (int j = 0; j < 2; j++) {
            bfr[j] = *(const bf16x8*)&Bs[wc * 32 + j * 16 + l15][lhi * 8];
            afr[j] = *(const bf16x8*)&As[wr * 32 + j * 16 + l15][lhi * 8];
        }
        #pragma unroll
        for (int i = 0; i < 2; i++)
            #pragma unroll
            for (int j = 0; j < 2; j++)
                acc[i][j] = __builtin_amdgcn_mfma_f32_16x16x32_bf16(afr[i], bfr[j], acc[i][j], 0, 0, 0);
        __syncthreads();
    }
    #pragma unroll
    for (int i = 0; i < 2; i++) {
        int row = row0 + wr * 32 + i * 16 + lhi * 4;
        #pragma unroll
        for (int j = 0; j < 2; j++) {
            int col = col0 + wc * 32 + j * 16 + l15;
            float bv = bias[col];
            #pragma unroll
            for (int r = 0; r < 4; r++) {
                float v = acc[i][j][r] + bv;
                if (OUT_BF16) ((u16*)out)[(size_t)(row + r) * N + col] = f2b(v);
                else          ((float*)out)[(size_t)(row + r) * N + col] = v;
            }
        }
    }
}

// ---- depthwise 3x3 (SAME), bf16 in/out, fp32 accum, 8 ch/thread ----
__global__ __launch_bounds__(256) void dwconv_b(const u16* __restrict__ qkv_b,
        const float* __restrict__ dww, const float* __restrict__ dwb,
        u16* __restrict__ out) {
    int idx = blockIdx.x * 256 + threadIdx.x;       // 8192*96
    int c8 = (idx % 96) * 8;
    int pix = idx / 96;
    int w = pix & 63, h = (pix >> 6) & 63, b = pix >> 12;
    float acc[8];
    #pragma unroll
    for (int j = 0; j < 8; j++) acc[j] = dwb[c8 + j];
    #pragma unroll
    for (int ky = 0; ky < 3; ky++) {
        int hh = h + ky - 1;
        if (hh < 0 || hh >= 64) continue;
        #pragma unroll
        for (int kx = 0; kx < 3; kx++) {
            int ww = w + kx - 1;
            if (ww < 0 || ww >= 64) continue;
            bf16x8 v = *(const bf16x8*)&qkv_b[((size_t)((b * 64 + hh) * 64 + ww)) * 768 + c8];
            #pragma unroll
            for (int j = 0; j < 8; j++)
                acc[j] += b2f((u16)v[j]) * dww[(ky * 3 + kx) * 768 + c8 + j];
        }
    }
    bf16x8 o;
    #pragma unroll
    for (int j = 0; j < 8; j++) o[j] = (short)f2b(acc[j]);
    *(bf16x8*)&out[(size_t)idx * 8] = o;
}

// ---- offsets+mask via im2col MFMA GEMM, K-split x4 for occupancy ----
// grid 1024: blockIdx&3 = K-quarter (quarter 0 adds bias -> om0; others -> om1..3)
__global__ __launch_bounds__(256) void offmask_mfma(const u16* __restrict__ qdw_b,
        const u16* __restrict__ cwT_b, const float* __restrict__ cb,
        float* __restrict__ om0, float* __restrict__ om1,
        float* __restrict__ om2, float* __restrict__ om3) {
    __shared__ u16 As[32][40];
    __shared__ u16 Bs[160][40];
    int tid = threadIdx.x;
    int half = blockIdx.x & 3;
    int p0 = (blockIdx.x >> 2) * 32;
    int kbeg = half * 192;
    int kend = kbeg + 192;
    int wid = tid >> 6, lane = tid & 63;
    int wr = wid >> 1, wc = wid & 1;
    int l15 = lane & 15, lhi = lane >> 4;
    f32x4 acc[5] = {};
    for (int k0 = kbeg; k0 < kend; k0 += 32) {
        if (tid < 128) {
            int r = tid >> 2, kc = (tid & 3) * 8;
            int pixel = p0 + r;
            int w = pixel & 63, h = (pixel >> 6) & 63, b = pixel >> 12;
            bf16x8 v = {};
            if (k0 < 576) {
                int patch = k0 >> 6;
                int dy = patch / 3 - 1, dx = patch % 3 - 1;
                int hh = h + dy, ww = w + dx;
                if (hh >= 0 && hh < 64 && ww >= 0 && ww < 64)
                    v = *(const bf16x8*)&qdw_b[((size_t)((b * 64 + hh) * 64 + ww)) * 768 + (k0 & 63) + kc];
            } else {
                v = *(const bf16x8*)&qdw_b[((size_t)((b * 64 + h) * 64 + w)) * 768 + 64 + (k0 - 576) + kc];
            }
            *(bf16x8*)&As[r][kc] = v;
        }
        for (int idx = tid; idx < 640; idx += 256) {
            int r = idx >> 2, kc = (idx & 3) * 8;
            *(bf16x8*)&Bs[r][kc] = *(const bf16x8*)&cwT_b[r * 768 + k0 + kc];
        }
        __syncthreads();
        bf16x8 afr = *(const bf16x8*)&As[wr * 16 + l15][lhi * 8];
        #pragma unroll
        for (int j = 0; j < 5; j++) {
            bf16x8 bfr = *(const bf16x8*)&Bs[wc * 80 + j * 16 + l15][lhi * 8];
            acc[j] = __builtin_amdgcn_mfma_f32_16x16x32_bf16(afr, bfr, acc[j], 0, 0, 0);
        }
        __syncthreads();
    }
    float* dst = (half == 0) ? om0 : (half == 1) ? om1 : (half == 2) ? om2 : om3;
    int row = p0 + wr * 16 + lhi * 4;
    #pragma unroll
    for (int j = 0; j < 5; j++) {
        int col = wc * 80 + j * 16 + l15;
        float bv = (half == 0) ? cb[col] : 0.f;
        #pragma unroll
        for (int r = 0; r < 4; r++)
            dst[(size_t)(row + r) * 160 + col] = acc[j][r] + bv;
    }
}

// ---- per-(pix,g,k) sample params from the 4 K-split partials ----
__device__ __forceinline__ float4 pt_params(const float* __restrict__ om0,
        const float* __restrict__ om1, const float* __restrict__ om2,
        const float* __restrict__ om3, int pix, int g, int k) {
    int w = pix & 63, h = (pix >> 6) & 63;
    size_t rowb = (size_t)pix * 160;
    size_t db = rowb + g * 18 + 2 * k;
    f32x2 d0 = *(const f32x2*)&om0[db];
    f32x2 d1 = *(const f32x2*)&om1[db];
    f32x2 d2 = *(const f32x2*)&om2[db];
    f32x2 d3 = *(const f32x2*)&om3[db];
    float m = om0[rowb + 144 + k] + om1[rowb + 144 + k]
            + om2[rowb + 144 + k] + om3[rowb + 144 + k];
    float dx = d0.x + d1.x + d2.x + d3.x;
    float dy = d0.y + d1.y + d2.y + d3.y;
    float cx = fminf(fmaxf((float)w + dx, 0.f), 63.f);
    float cy = fminf(fmaxf((float)h + dy, 0.f), 63.f);
    float x0f = floorf(cx), y0f = floorf(cy);
    int x0 = (int)x0f, y0 = (int)y0f;
    u32 pk = (u32)((pix & ~4095) | (y0 << 6) | x0)
           | ((x0 < 63) ? 0x10000u : 0u) | ((y0 < 63) ? 0x20000u : 0u);
    float4 o;
    o.x = __uint_as_float(pk);
    o.y = cx - x0f;
    o.z = cy - y0f;
    o.w = m;
    return o;
}

// ---- deformable gather + softmax + V sum + fused projection ----
// Block = 4 pixels x 8 groups (32 units x 8 lanes); XCD-chunked block swizzle.
// Phase 1: 288 point-params into LDS. Phase 2: gather+softmax+PV -> att_lds.
// Phase 3: out[4][256] = att[4][256] @ projT^T + proj_b via MFMA (A rows 4..15 = 0).
__global__ __launch_bounds__(256) void deform_attn(const u16* __restrict__ qdw_b,
        const float* __restrict__ om0, const float* __restrict__ om1,
        const float* __restrict__ om2, const float* __restrict__ om3,
        const u16* __restrict__ projT, const float* __restrict__ proj_b,
        float* __restrict__ outp) {
    __shared__ float4 ptp[288];
    __shared__ u16 att_lds[4][264];   // +8 u16 pad -> 528B row stride (bank shift)
    int tid = threadIdx.x;
    int bid = blockIdx.x;                       // grid 2048 (%8==0)
    int sbid = (bid & 7) * 256 + (bid >> 3);    // bijective XCD-chunked swizzle
    // phase 1: 288 point-params (32 units x 9 points)
    for (int j = tid; j < 288; j += 256) {
        int u = j / 9, k = j % 9;
        int ppix = sbid * 4 + (u >> 3);
        ptp[j] = pt_params(om0, om1, om2, om3, ppix, u & 7, k);
    }
    __syncthreads();
    int t = tid >> 3;                           // unit-in-block 0..31
    int cl = tid & 7;                           // channel-quad lane
    int g = t & 7;
    int prow = t >> 3;                          // pixel row-in-block 0..3
    int pix = sbid * 4 + prow;
    const float scale = 0.17677669529663687f;   // 32^-0.5
    int c0 = g * 32 + 4 * cl;
    u32x2 qu = *(const u32x2*)&qdw_b[(size_t)pix * 768 + c0];
    f32x2 qa = unpk2(qu.x) * scale;
    f32x2 qb = unpk2(qu.y) * scale;
    const char* base = (const char*)qdw_b;
    u32 ckb = (u32)(512 + c0 * 2);   // this lane's k-quad byte offset in a pixel row
    float logit[KPT];
    f32x2 va[KPT], vb[KPT];
    #pragma unroll
    for (int k_ = 0; k_ < KPT; k_++) {
        float4 q4 = ptp[t * 9 + k_];              // uniform across the 8-lane group
        u32 pk = __float_as_uint(q4.x);
        float wx = q4.y, wy = q4.z, m = q4.w;
        u32 o00 = (pk & 0xFFFFu) * 1536u + ckb;
        u32 dX = (pk & 0x10000u) ? 1536u : 0u;
        u32 dY = (pk & 0x20000u) ? 98304u : 0u;
        u32 o01 = o00 + dX, o10 = o00 + dY, o11 = o00 + dY + dX;
        u32x2 K00 = *(const u32x2*)(base + o00);
        u32x2 V00 = *(const u32x2*)(base + o00 + 512);
        u32x2 K01 = *(const u32x2*)(base + o01);
        u32x2 V01 = *(const u32x2*)(base + o01 + 512);
        u32x2 K10 = *(const u32x2*)(base + o10);
        u32x2 V10 = *(const u32x2*)(base + o10 + 512);
        u32x2 K11 = *(const u32x2*)(base + o11);
        u32x2 V11 = *(const u32x2*)(base + o11 + 512);
        float w00 = (1.f - wx) * (1.f - wy), w01 = wx * (1.f - wy);
        float w10 = (1.f - wx) * wy,         w11 = wx * wy;
        f32x2 ka = unpk2(K00.x) * w00 + unpk2(K01.x) * w01
                 + unpk2(K10.x) * w10 + unpk2(K11.x) * w11;
        f32x2 kb = unpk2(K00.y) * w00 + unpk2(K01.y) * w01
                 + unpk2(K10.y) * w10 + unpk2(K11.y) * w11;
        f32x2 vva = unpk2(V00.x) * w00 + unpk2(V01.x) * w01
                  + unpk2(V10.x) * w10 + unpk2(V11.x) * w11;
        f32x2 vvb = unpk2(V00.y) * w00 + unpk2(V01.y) * w01
                  + unpk2(V10.y) * w10 + unpk2(V11.y) * w11;
        f32x2 pr = qa * ka + qb * kb;
        float part = pr.x + pr.y;
        part += __shfl_xor(part, 4);
        part += __shfl_xor(part, 2);
        part += __shfl_xor(part, 1);
        logit[k_] = part * m;
        va[k_] = vva * m;
        vb[k_] = vvb * m;
    }
    float mx = fmaxf(fmaxf(fmaxf(logit[0], logit[1]), fmaxf(logit[2], logit[3])),
                     fmaxf(fmaxf(logit[4], logit[5]),
                           fmaxf(fmaxf(logit[6], logit[7]), logit[8])));
    float s = 0.f;
    #pragma unroll
    for (int k_ = 0; k_ < KPT; k_++) { logit[k_] = __expf(logit[k_] - mx); s += logit[k_]; }
    float inv = 1.f / s;
    f32x2 oa = {0.f, 0.f}, ob = {0.f, 0.f};
    #pragma unroll
    for (int k_ = 0; k_ < KPT; k_++) { oa += va[k_] * logit[k_]; ob += vb[k_] * logit[k_]; }
    oa *= inv; ob *= inv;
    // attention output -> LDS (bf16, same rounding as the old attn_b buffer)
    att_lds[prow][c0 + 0] = f2b(oa.x);
    att_lds[prow][c0 + 1] = f2b(oa.y);
    att_lds[prow][c0 + 2] = f2b(ob.x);
    att_lds[prow][c0 + 3] = f2b(ob.y);
    __syncthreads();
    // phase 3: projection. wave wid owns cols [wid*64, wid*64+64).
    int wid = tid >> 6, lane = tid & 63;
    int l15 = lane & 15, lhi = lane >> 4;
    f32x4 pacc[4] = {};
    #pragma unroll
    for (int k0 = 0; k0 < 8; k0++) {
        bf16x8 afr = {};
        if (l15 < 4) afr = *(const bf16x8*)&att_lds[l15][k0 * 32 + lhi * 8];
        #pragma unroll
        for (int n16 = 0; n16 < 4; n16++) {
            int ncol = wid * 64 + n16 * 16 + l15;
            bf16x8 bfr = *(const bf16x8*)&projT[(size_t)ncol * 256 + k0 * 32 + lhi * 8];
            pacc[n16] = __builtin_amdgcn_mfma_f32_16x16x32_bf16(afr, bfr, pacc[n16], 0, 0, 0);
        }
    }
    if (lhi == 0) {   // C/D rows 0..3 live in lanes 0..15, regs 0..3
        #pragma unroll
        for (int n16 = 0; n16 < 4; n16++) {
            int ncol = wid * 64 + n16 * 16 + l15;
            float bv = proj_b[ncol];
            #pragma unroll
            for (int r = 0; r < 4; r++)
                outp[(size_t)(sbid * 4 + r) * 256 + ncol] = pacc[n16][r] + bv;
        }
    }
}

extern "C" void kernel_launch(void* const* d_in, const int* in_sizes, int n_in,
                              void* d_out, int out_size, void* d_ws, size_t ws_size,
                              hipStream_t stream) {
    const float* x            = (const float*)d_in[0];
    const float* qkv_w        = (const float*)d_in[1];
    const float* qkv_b        = (const float*)d_in[2];
    const float* dw_w         = (const float*)d_in[3];
    const float* dw_b         = (const float*)d_in[4];
    const float* off_pconv_w  = (const float*)d_in[5];
    const float* off_w        = (const float*)d_in[6];
    const float* off_b        = (const float*)d_in[7];
    const float* mask_pconv_w = (const float*)d_in[8];
    const float* mask_w       = (const float*)d_in[9];
    const float* mask_b       = (const float*)d_in[10];
    const float* proj_w       = (const float*)d_in[11];
    const float* proj_b       = (const float*)d_in[12];

    char* ws = (char*)d_ws;
    size_t off = 0;
    u16*   qkv_wT_b   = (u16*)(ws + off);                 off += 768ull*256*2;
    u16*   proj_wT_b  = (u16*)(ws + off);                 off += 256ull*256*2;
    u16*   qkv_bf     = (u16*)(ws + off);                 off += 8192ull*768*2;
    u16*   qdw_b      = (u16*)(ws + off);                 off += 8192ull*768*2;
    u16*   cwT_b      = (u16*)(ws + off);                 off += 160ull*768*2;
    float* cb         = (float*)(ws + off);               off += 256*4;
    float* om0        = (float*)(ws + off);               off += 8192ull*160*4;
    float* om1        = (float*)(ws + off);               off += 8192ull*160*4;
    float* om2        = (float*)(ws + off);               off += 8192ull*160*4;
    float* om3        = (float*)(ws + off);               off += 8192ull*160*4;

    // 1) weight convert/transpose + composite offset/mask weights (one launch)
    prep_weights<<<1792, 256, 0, stream>>>(qkv_w, proj_w, off_pconv_w, off_w, off_b,
                                           mask_pconv_w, mask_w, mask_b,
                                           qkv_wT_b, proj_wT_b, cwT_b, cb);
    // 2) qkv = x @ qkv_w + b   (fp32 A converted in staging, bf16 MFMA, bf16 out)
    mfma_gemm<true, true, 256><<<dim3(128, 12), 256, 0, stream>>>(x, qkv_wT_b, qkv_b,
                                                                  qkv_bf, 768);
    // 3) depthwise 3x3
    dwconv_b<<<3072, 256, 0, stream>>>(qkv_bf, dw_w, dw_b, qdw_b);
    // 4) offsets + mask (im2col MFMA, K-split x4 in one grid)
    offmask_mfma<<<1024, 256, 0, stream>>>(qdw_b, cwT_b, cb, om0, om1, om2, om3);
    // 5) deformable attention + fused projection (writes d_out directly)
    deform_attn<<<2048, 256, 0, stream>>>(qdw_b, om0, om1, om2, om3,
                                          proj_wT_b, proj_b, (float*)d_out);
}